// Round 1
// baseline (545.227 us; speedup 1.0000x reference)
//
#include <hip/hip_runtime.h>
#include <math.h>

// Problem constants
constexpr int C_ = 128, A_ = 64, K_ = 24, S_ = 4;
constexpr int NP_ = 276;          // K*(K-1)/2 neighbor pairs
constexpr int FAEV = 384;         // 64 radial + 320 angular
constexpr float RCR = 5.2f, RCA = 3.5f;
constexpr float ETA_R = 16.0f, ETA_A = 8.0f;
constexpr float PI_F = 3.14159265358979323846f;

#define MCHUNK 16

__global__ void zero_out_kernel(float* out) {
    int t = threadIdx.x;
    if (t < C_) out[t] = 0.0f;
}

__launch_bounds__(256)
__global__ void aev_mlp_kernel(const int* __restrict__ element_idxs,
                               const int* __restrict__ neighbor_idxs,
                               const float* __restrict__ distances,
                               const float* __restrict__ diff_vectors,
                               const float* __restrict__ W1, const float* __restrict__ b1,
                               const float* __restrict__ W2, const float* __restrict__ b2,
                               const float* __restrict__ W3, const float* __restrict__ b3,
                               const float* __restrict__ W4, const float* __restrict__ b4,
                               float* __restrict__ out)
{
    const int bx = blockIdx.x;
    const int c = bx >> 2;       // molecule
    const int s = bx & 3;        // species this block handles
    const int t = threadIdx.x;

    __shared__ int   elem_s[A_];
    __shared__ int   list_s[A_];
    __shared__ int   count_s;
    __shared__ float aev_s[MCHUNK][FAEV];
    __shared__ float h1_s[MCHUNK][160];
    __shared__ float h2_s[MCHUNK][128];
    __shared__ float h3_s[MCHUNK][96];
    __shared__ float d_s[MCHUNK][K_];
    __shared__ float fcr_s[MCHUNK][K_];
    __shared__ float fca_s[MCHUNK][K_];
    __shared__ float vx_s[MCHUNK][K_], vy_s[MCHUNK][K_], vz_s[MCHUNK][K_];
    __shared__ int   spec_s[MCHUNK][K_];

    if (t < A_) elem_s[t] = element_idxs[c * A_ + t];
    __syncthreads();
    if (t == 0) {
        int n = 0;
        for (int a = 0; a < A_; ++a) if (elem_s[a] == s) list_s[n++] = a;
        count_s = n;
    }
    __syncthreads();
    const int count = count_s;
    if (count == 0) return;

    const float* W1s = W1 + s * (FAEV * 160);
    const float* b1s = b1 + s * 160;
    const float* W2s = W2 + s * (160 * 128);
    const float* b2s = b2 + s * 128;
    const float* W3s = W3 + s * (128 * 96);
    const float* b3s = b3 + s * 96;
    const float* W4s = W4 + s * 96;
    const float* b4s = b4 + s;

    const int nchunk = (count + MCHUNK - 1) / MCHUNK;

    for (int ch = 0; ch < nchunk; ++ch) {
        const int m0 = ch * MCHUNK;
        const int Mcur = min(MCHUNK, count - m0);

        // ---- zero AEV accumulators ----
        for (int i = t; i < MCHUNK * FAEV; i += 256)
            ((float*)aev_s)[i] = 0.0f;

        // ---- load neighbor data for this chunk ----
        for (int idx = t; idx < MCHUNK * K_; idx += 256) {
            int m = idx / K_, k = idx % K_;
            if (m < Mcur) {
                int a = list_s[m0 + m];
                int base = (c * A_ + a) * K_ + k;
                int nb = neighbor_idxs[base];
                float d = distances[base];
                d_s[m][k] = d;
                spec_s[m][k] = elem_s[nb];
                vx_s[m][k] = diff_vectors[base * 3 + 0];
                vy_s[m][k] = diff_vectors[base * 3 + 1];
                vz_s[m][k] = diff_vectors[base * 3 + 2];
                fcr_s[m][k] = (d < RCR) ? (0.5f * cosf(PI_F * d / RCR) + 0.5f) : 0.0f;
                fca_s[m][k] = (d < RCA) ? (0.5f * cosf(PI_F * d / RCA) + 0.5f) : 0.0f;
            } else {
                d_s[m][k] = 1.0f; spec_s[m][k] = 0;
                vx_s[m][k] = 0.f; vy_s[m][k] = 0.f; vz_s[m][k] = 0.f;
                fcr_s[m][k] = 0.f; fca_s[m][k] = 0.f;
            }
        }
        __syncthreads();

        // ---- radial AEV: 16 atoms x 24 nbrs x 16 shells ----
        for (int rep = 0; rep < (MCHUNK * K_ * 16) / 256; ++rep) {
            int idx = rep * 256 + t;            // < 16*384 = 6144
            int m = idx / (K_ * 16);
            int rem = idx - m * (K_ * 16);
            int k = rem >> 4, r = rem & 15;
            if (m < Mcur) {
                float d = d_s[m][k];
                float shf = 0.9f + 0.26875f * (float)r;
                float df = d - shf;
                float val = 0.25f * expf(-ETA_R * df * df) * fcr_s[m][k];
                atomicAdd(&aev_s[m][spec_s[m][k] * 16 + r], val);
            }
        }

        // ---- angular AEV: per atom, 276 pairs x 32 feats ----
        {
            const float CZ[8] = { 0.98078528f,  0.83146961f,  0.55557023f,  0.19509032f,
                                 -0.19509032f, -0.55557023f, -0.83146961f, -0.98078528f};
            const float SZ[8] = { 0.19509032f,  0.55557023f,  0.83146961f,  0.98078528f,
                                  0.98078528f,  0.83146961f,  0.55557023f,  0.19509032f};
            for (int m = (t >> 5); m < MCHUNK; m += 8) {
                if (m >= Mcur) continue;
                for (int p = (t & 31); p < NP_; p += 32) {
                    int j = (int)((47.0f - sqrtf(2209.0f - 8.0f * (float)p)) * 0.5f);
                    while (j * (47 - j) / 2 > p) --j;
                    while ((j + 1) * (46 - j) / 2 <= p) ++j;
                    int k2 = p - j * (47 - j) / 2 + j + 1;

                    float fc12 = fca_s[m][j] * fca_s[m][k2];
                    if (fc12 == 0.0f) continue;
                    float d1 = d_s[m][j], d2 = d_s[m][k2];
                    float dot = vx_s[m][j] * vx_s[m][k2]
                              + vy_s[m][j] * vy_s[m][k2]
                              + vz_s[m][j] * vz_s[m][k2];
                    float ca = 0.95f * dot / (d1 * d2);
                    float sa = sqrtf(fmaxf(0.0f, 1.0f - ca * ca));
                    float hs = 0.5f * (d1 + d2);
                    float f2v[4];
                    #pragma unroll
                    for (int y = 0; y < 4; ++y) {
                        float dd = hs - (0.9f + 0.65f * (float)y);
                        f2v[y] = expf(-ETA_A * dd * dd);
                    }
                    int sj = spec_s[m][j], sk = spec_s[m][k2];
                    int lo = min(sj, sk), hi = max(sj, sk);
                    int pidx = lo * (9 - lo) / 2 + (hi - lo);
                    float* dst = &aev_s[m][64 + pidx * 32];
                    float t2 = 2.0f * fc12;
                    #pragma unroll
                    for (int z = 0; z < 8; ++z) {
                        float x = 0.5f * (1.0f + ca * CZ[z] + sa * SZ[z]);
                        float x2 = x * x, x4 = x2 * x2, x8 = x4 * x4, x16 = x8 * x8;
                        float g = t2 * (x16 * x16);
                        #pragma unroll
                        for (int y = 0; y < 4; ++y)
                            atomicAdd(&dst[z * 4 + y], g * f2v[y]);
                    }
                }
            }
        }
        __syncthreads();

        // ---- layer 1: 384 -> 160 ----
        if (t < 160) {
            float acc[MCHUNK];
            #pragma unroll
            for (int m = 0; m < MCHUNK; ++m) acc[m] = 0.0f;
            for (int f = 0; f < FAEV; f += 4) {
                float w0 = W1s[(f + 0) * 160 + t];
                float w1 = W1s[(f + 1) * 160 + t];
                float w2 = W1s[(f + 2) * 160 + t];
                float w3 = W1s[(f + 3) * 160 + t];
                #pragma unroll
                for (int m = 0; m < MCHUNK; ++m) {
                    float4 av = *(const float4*)&aev_s[m][f];
                    acc[m] += av.x * w0 + av.y * w1 + av.z * w2 + av.w * w3;
                }
            }
            float bb = b1s[t];
            #pragma unroll
            for (int m = 0; m < MCHUNK; ++m) {
                float x = acc[m] + bb;
                h1_s[m][t] = (x > 0.0f) ? x : 0.1f * expm1f(10.0f * x);
            }
        }
        __syncthreads();

        // ---- layer 2: 160 -> 128 ----
        if (t < 128) {
            float acc[MCHUNK];
            #pragma unroll
            for (int m = 0; m < MCHUNK; ++m) acc[m] = 0.0f;
            for (int f = 0; f < 160; f += 4) {
                float w0 = W2s[(f + 0) * 128 + t];
                float w1 = W2s[(f + 1) * 128 + t];
                float w2 = W2s[(f + 2) * 128 + t];
                float w3 = W2s[(f + 3) * 128 + t];
                #pragma unroll
                for (int m = 0; m < MCHUNK; ++m) {
                    float4 av = *(const float4*)&h1_s[m][f];
                    acc[m] += av.x * w0 + av.y * w1 + av.z * w2 + av.w * w3;
                }
            }
            float bb = b2s[t];
            #pragma unroll
            for (int m = 0; m < MCHUNK; ++m) {
                float x = acc[m] + bb;
                h2_s[m][t] = (x > 0.0f) ? x : 0.1f * expm1f(10.0f * x);
            }
        }
        __syncthreads();

        // ---- layer 3: 128 -> 96 ----
        if (t < 96) {
            float acc[MCHUNK];
            #pragma unroll
            for (int m = 0; m < MCHUNK; ++m) acc[m] = 0.0f;
            for (int f = 0; f < 128; f += 4) {
                float w0 = W3s[(f + 0) * 96 + t];
                float w1 = W3s[(f + 1) * 96 + t];
                float w2 = W3s[(f + 2) * 96 + t];
                float w3 = W3s[(f + 3) * 96 + t];
                #pragma unroll
                for (int m = 0; m < MCHUNK; ++m) {
                    float4 av = *(const float4*)&h2_s[m][f];
                    acc[m] += av.x * w0 + av.y * w1 + av.z * w2 + av.w * w3;
                }
            }
            float bb = b3s[t];
            #pragma unroll
            for (int m = 0; m < MCHUNK; ++m) {
                float x = acc[m] + bb;
                h3_s[m][t] = (x > 0.0f) ? x : 0.1f * expm1f(10.0f * x);
            }
        }
        __syncthreads();

        // ---- layer 4: 96 -> 1, accumulate per molecule ----
        if (t < Mcur) {
            float e = b4s[0];
            for (int f = 0; f < 96; ++f) e += h3_s[t][f] * W4s[f];
            atomicAdd(&out[c], e);
        }
        __syncthreads();   // protect LDS before next chunk overwrites it
    }
}

extern "C" void kernel_launch(void* const* d_in, const int* in_sizes, int n_in,
                              void* d_out, int out_size, void* d_ws, size_t ws_size,
                              hipStream_t stream) {
    const int*   element_idxs  = (const int*)d_in[0];
    const int*   neighbor_idxs = (const int*)d_in[1];
    const float* distances     = (const float*)d_in[2];
    const float* diff_vectors  = (const float*)d_in[3];
    const float* W1 = (const float*)d_in[4];
    const float* b1 = (const float*)d_in[5];
    const float* W2 = (const float*)d_in[6];
    const float* b2 = (const float*)d_in[7];
    const float* W3 = (const float*)d_in[8];
    const float* b3 = (const float*)d_in[9];
    const float* W4 = (const float*)d_in[10];
    const float* b4 = (const float*)d_in[11];
    float* out = (float*)d_out;

    hipLaunchKernelGGL(zero_out_kernel, dim3(1), dim3(128), 0, stream, out);
    hipLaunchKernelGGL(aev_mlp_kernel, dim3(C_ * S_), dim3(256), 0, stream,
                       element_idxs, neighbor_idxs, distances, diff_vectors,
                       W1, b1, W2, b2, W3, b3, W4, b4, out);
}

// Round 2
// 407.752 us; speedup vs baseline: 1.3372x; 1.3372x over previous
//
#include <hip/hip_runtime.h>
#include <math.h>

// Problem constants
constexpr int C_ = 128, A_ = 64, K_ = 24, S_ = 4;
constexpr int FAEV = 384;         // 64 radial + 320 angular
constexpr float RCR = 5.2f, RCA = 3.5f;
constexpr float ETA_R = 16.0f, ETA_A = 8.0f;
constexpr float PI_F = 3.14159265358979323846f;

#define MCHUNK 16

__global__ void zero_out_kernel(float* out) {
    int t = threadIdx.x;
    if (t < C_) out[t] = 0.0f;
}

__launch_bounds__(256)
__global__ void aev_mlp_kernel(const int* __restrict__ element_idxs,
                               const int* __restrict__ neighbor_idxs,
                               const float* __restrict__ distances,
                               const float* __restrict__ diff_vectors,
                               const float* __restrict__ W1, const float* __restrict__ b1,
                               const float* __restrict__ W2, const float* __restrict__ b2,
                               const float* __restrict__ W3, const float* __restrict__ b3,
                               const float* __restrict__ W4, const float* __restrict__ b4,
                               float* __restrict__ out)
{
    const int bx = blockIdx.x;
    const int c = bx >> 2;       // molecule
    const int s = bx & 3;        // species this block handles
    const int t = threadIdx.x;

    __shared__ int    elem_s[A_];
    __shared__ int    list_s[A_];
    __shared__ int    count_s;
    __shared__ float  aev_s[MCHUNK][FAEV];     // also overlays h2 (16x128) + h3 (16x96)
    __shared__ float  h1_s[MCHUNK][160];
    __shared__ float4 u4_s[MCHUNK][K_];        // {ux, uy, uz, d}
    __shared__ float  fcr_s[MCHUNK][K_];
    __shared__ float  fca_s[MCHUNK][K_];
    __shared__ int    spec_s[MCHUNK][K_];
    __shared__ int    aidx_s[MCHUNK][K_];      // compacted active-neighbor indices
    __shared__ int    na_s[MCHUNK];

    float (*h2_s)[128] = (float(*)[128])&aev_s[0][0];
    float (*h3_s)[96]  = (float(*)[96])(&aev_s[0][0] + MCHUNK * 128);

    if (t < A_) elem_s[t] = element_idxs[c * A_ + t];
    __syncthreads();
    if (t == 0) {
        int n = 0;
        for (int a = 0; a < A_; ++a) if (elem_s[a] == s) list_s[n++] = a;
        count_s = n;
    }
    __syncthreads();
    const int count = count_s;
    if (count == 0) return;

    const float* W1s = W1 + s * (FAEV * 160);
    const float* b1s = b1 + s * 160;
    const float* W2s = W2 + s * (160 * 128);
    const float* b2s = b2 + s * 128;
    const float* W3s = W3 + s * (128 * 96);
    const float* b3s = b3 + s * 96;
    const float* W4s = W4 + s * 96;
    const float* b4s = b4 + s;

    // per-lane constants for the per-atom (half-wave) phases
    const int wave   = t >> 6;
    const int lane   = t & 63;
    const int half   = lane >> 5;
    const int slot   = wave * 2 + half;   // 0..7 : atom slot within round
    const int lane32 = lane & 31;
    const int zz = lane32 >> 2;           // angular z index 0..7
    const int yy = lane32 & 3;            // angular y index 0..3
    const float cz2 = 0.5f * __cosf(((float)zz + 0.5f) * (PI_F / 8.0f));
    const float sz2 = 0.5f * __sinf(((float)zz + 0.5f) * (PI_F / 8.0f));
    const float shfa_l = 0.9f + 0.65f * (float)yy;
    const float shfr_l = 0.9f + 0.26875f * (float)(lane32 & 15);
    const int   spg    = lane32 >> 4;     // 0 or 1 : radial species group

    const int nchunk = (count + MCHUNK - 1) / MCHUNK;

    for (int ch = 0; ch < nchunk; ++ch) {
        const int m0 = ch * MCHUNK;
        const int Mcur = min(MCHUNK, count - m0);

        // ---- phase 1: zero AEV + load/precompute neighbor data ----
        for (int i = t; i < MCHUNK * FAEV; i += 256)
            ((float*)aev_s)[i] = 0.0f;

        for (int idx = t; idx < MCHUNK * K_; idx += 256) {
            int m = idx / K_, k = idx % K_;
            if (m < Mcur) {
                int a = list_s[m0 + m];
                int base = (c * A_ + a) * K_ + k;
                int nb = neighbor_idxs[base];
                float d = distances[base];
                float inv = __builtin_amdgcn_rcpf(d);
                float4 u;
                u.x = diff_vectors[base * 3 + 0] * inv;
                u.y = diff_vectors[base * 3 + 1] * inv;
                u.z = diff_vectors[base * 3 + 2] * inv;
                u.w = d;
                u4_s[m][k] = u;
                spec_s[m][k] = elem_s[nb];
                fcr_s[m][k] = (d < RCR) ? (0.5f * __cosf(PI_F * d * (1.0f / RCR)) + 0.5f) : 0.0f;
                fca_s[m][k] = (d < RCA) ? (0.5f * __cosf(PI_F * d * (1.0f / RCA)) + 0.5f) : 0.0f;
            } else {
                u4_s[m][k] = make_float4(0.f, 0.f, 0.f, 1.f);
                spec_s[m][k] = 0;
                fcr_s[m][k] = 0.f;
                fca_s[m][k] = 0.f;
            }
        }
        __syncthreads();

        // ---- phase 2: compact active (fca>0) neighbor lists ----
        if (t < MCHUNK) {
            int n = 0;
            #pragma unroll
            for (int k = 0; k < K_; ++k)
                if (fca_s[t][k] > 0.0f) aidx_s[t][n++] = k;
            na_s[t] = n;
        }
        __syncthreads();

        // ---- phase 3: per-atom AEV, half-wave per atom, lane = feature ----
        for (int m = slot; m < MCHUNK; m += 8) {
            if (m >= Mcur) continue;

            // radial: lane owns features lane32 (species spg) and 32+lane32 (species 2+spg)
            {
                float acc0 = 0.0f, acc1 = 0.0f;
                #pragma unroll
                for (int k = 0; k < K_; ++k) {
                    float d   = u4_s[m][k].w;
                    float fcr = fcr_s[m][k];
                    int   sp  = spec_s[m][k];
                    float df  = d - shfr_l;
                    float term = 0.25f * __expf(-ETA_R * df * df) * fcr;
                    if (sp == spg)     acc0 += term;
                    if (sp == 2 + spg) acc1 += term;
                }
                aev_s[m][lane32]      = acc0;
                aev_s[m][32 + lane32] = acc1;
            }

            // angular: loop over active pairs; lane = (z,y) feature; pidx uniform per half-wave
            {
                const int na = na_s[m];
                for (int jj = 0; jj + 1 < na; ++jj) {
                    int j = aidx_s[m][jj];
                    float4 u1 = u4_s[m][j];
                    float fca1 = fca_s[m][j];
                    int   sj   = spec_s[m][j];
                    for (int kk = jj + 1; kk < na; ++kk) {
                        int k2 = aidx_s[m][kk];
                        float4 u2 = u4_s[m][k2];
                        float fca2 = fca_s[m][k2];
                        int   sk   = spec_s[m][k2];

                        float ca = 0.95f * (u1.x * u2.x + u1.y * u2.y + u1.z * u2.z);
                        float sa = sqrtf(fmaxf(0.0f, 1.0f - ca * ca));
                        float hs = 0.5f * (u1.w + u2.w);
                        float t2 = 2.0f * fca1 * fca2;
                        float dd = hs - shfa_l;
                        float f2 = __expf(-ETA_A * dd * dd);
                        float x  = 0.5f + ca * cz2 + sa * sz2;
                        float x2 = x * x, x4 = x2 * x2, x8 = x4 * x4, x16 = x8 * x8;
                        int lo = min(sj, sk), hi = max(sj, sk);
                        int pidx = lo * (9 - lo) / 2 + (hi - lo);
                        aev_s[m][64 + pidx * 32 + lane32] += (x16 * x16) * f2 * t2;
                    }
                }
            }
        }
        __syncthreads();

        // ---- layer 1: 384 -> 160 ----
        if (t < 160) {
            float acc[MCHUNK];
            #pragma unroll
            for (int m = 0; m < MCHUNK; ++m) acc[m] = 0.0f;
            for (int f = 0; f < FAEV; f += 4) {
                float w0 = W1s[(f + 0) * 160 + t];
                float w1 = W1s[(f + 1) * 160 + t];
                float w2 = W1s[(f + 2) * 160 + t];
                float w3 = W1s[(f + 3) * 160 + t];
                #pragma unroll
                for (int m = 0; m < MCHUNK; ++m) {
                    float4 av = *(const float4*)&aev_s[m][f];
                    acc[m] += av.x * w0 + av.y * w1 + av.z * w2 + av.w * w3;
                }
            }
            float bb = b1s[t];
            #pragma unroll
            for (int m = 0; m < MCHUNK; ++m) {
                float x = acc[m] + bb;
                h1_s[m][t] = (x > 0.0f) ? x : 0.1f * expm1f(10.0f * x);
            }
        }
        __syncthreads();   // after this, aev_s is dead -> reuse as h2/h3

        // ---- layer 2: 160 -> 128 (writes h2 overlay on aev) ----
        if (t < 128) {
            float acc[MCHUNK];
            #pragma unroll
            for (int m = 0; m < MCHUNK; ++m) acc[m] = 0.0f;
            for (int f = 0; f < 160; f += 4) {
                float w0 = W2s[(f + 0) * 128 + t];
                float w1 = W2s[(f + 1) * 128 + t];
                float w2 = W2s[(f + 2) * 128 + t];
                float w3 = W2s[(f + 3) * 128 + t];
                #pragma unroll
                for (int m = 0; m < MCHUNK; ++m) {
                    float4 av = *(const float4*)&h1_s[m][f];
                    acc[m] += av.x * w0 + av.y * w1 + av.z * w2 + av.w * w3;
                }
            }
            float bb = b2s[t];
            #pragma unroll
            for (int m = 0; m < MCHUNK; ++m) {
                float x = acc[m] + bb;
                h2_s[m][t] = (x > 0.0f) ? x : 0.1f * expm1f(10.0f * x);
            }
        }
        __syncthreads();

        // ---- layer 3: 128 -> 96 (writes h3 overlay) ----
        if (t < 96) {
            float acc[MCHUNK];
            #pragma unroll
            for (int m = 0; m < MCHUNK; ++m) acc[m] = 0.0f;
            for (int f = 0; f < 128; f += 4) {
                float w0 = W3s[(f + 0) * 96 + t];
                float w1 = W3s[(f + 1) * 96 + t];
                float w2 = W3s[(f + 2) * 96 + t];
                float w3 = W3s[(f + 3) * 96 + t];
                #pragma unroll
                for (int m = 0; m < MCHUNK; ++m) {
                    float4 av = *(const float4*)&h2_s[m][f];
                    acc[m] += av.x * w0 + av.y * w1 + av.z * w2 + av.w * w3;
                }
            }
            float bb = b3s[t];
            #pragma unroll
            for (int m = 0; m < MCHUNK; ++m) {
                float x = acc[m] + bb;
                h3_s[m][t] = (x > 0.0f) ? x : 0.1f * expm1f(10.0f * x);
            }
        }
        __syncthreads();

        // ---- layer 4: 96 -> 1, accumulate per molecule ----
        if (t < Mcur) {
            float e = b4s[0];
            for (int f = 0; f < 96; ++f) e += h3_s[t][f] * W4s[f];
            atomicAdd(&out[c], e);
        }
        __syncthreads();   // protect LDS before next chunk overwrites it
    }
}

extern "C" void kernel_launch(void* const* d_in, const int* in_sizes, int n_in,
                              void* d_out, int out_size, void* d_ws, size_t ws_size,
                              hipStream_t stream) {
    const int*   element_idxs  = (const int*)d_in[0];
    const int*   neighbor_idxs = (const int*)d_in[1];
    const float* distances     = (const float*)d_in[2];
    const float* diff_vectors  = (const float*)d_in[3];
    const float* W1 = (const float*)d_in[4];
    const float* b1 = (const float*)d_in[5];
    const float* W2 = (const float*)d_in[6];
    const float* b2 = (const float*)d_in[7];
    const float* W3 = (const float*)d_in[8];
    const float* b3 = (const float*)d_in[9];
    const float* W4 = (const float*)d_in[10];
    const float* b4 = (const float*)d_in[11];
    float* out = (float*)d_out;

    hipLaunchKernelGGL(zero_out_kernel, dim3(1), dim3(128), 0, stream, out);
    hipLaunchKernelGGL(aev_mlp_kernel, dim3(C_ * S_), dim3(256), 0, stream,
                       element_idxs, neighbor_idxs, distances, diff_vectors,
                       W1, b1, W2, b2, W3, b3, W4, b4, out);
}

// Round 3
// 336.212 us; speedup vs baseline: 1.6217x; 1.2128x over previous
//
#include <hip/hip_runtime.h>
#include <math.h>

// Problem constants
constexpr int C_ = 128, A_ = 64, K_ = 24, S_ = 4;
constexpr int FAEV = 384;         // 64 radial + 320 angular
constexpr float RCR = 5.2f, RCA = 3.5f;
constexpr float ETA_R = 16.0f, ETA_A = 8.0f;
constexpr float PI_F = 3.14159265358979323846f;

#define MCHUNK 8

__global__ void zero_out_kernel(float* out) {
    int t = threadIdx.x;
    if (t < C_) out[t] = 0.0f;
}

__launch_bounds__(256)
__global__ void aev_mlp_kernel(const int* __restrict__ element_idxs,
                               const int* __restrict__ neighbor_idxs,
                               const float* __restrict__ distances,
                               const float* __restrict__ diff_vectors,
                               const float* __restrict__ W1, const float* __restrict__ b1,
                               const float* __restrict__ W2, const float* __restrict__ b2,
                               const float* __restrict__ W3, const float* __restrict__ b3,
                               const float* __restrict__ W4, const float* __restrict__ b4,
                               float* __restrict__ out)
{
    const int bx  = blockIdx.x;
    const int c   = bx >> 3;       // molecule
    const int s   = (bx >> 1) & 3; // species this block handles
    const int ch0 = bx & 1;        // chunk parity (grid-stride by 2)
    const int t   = threadIdx.x;

    __shared__ int    elem_s[A_];
    __shared__ int    list_s[A_];
    __shared__ int    count_s;
    __shared__ float  aev_s[MCHUNK][FAEV];     // overlays h2 (8x128) + h3 (8x96) later
    __shared__ float  h1_s[MCHUNK][160];
    __shared__ float4 u4_s[MCHUNK][K_];        // {ux, uy, uz, d}
    __shared__ float  fcr_s[MCHUNK][K_];
    __shared__ float  fca_s[MCHUNK][K_];
    __shared__ int    spec_s[MCHUNK][K_];
    __shared__ int    bidx_s[MCHUNK][S_][K_];  // per-species active neighbor lists
    __shared__ int    nsp_s[MCHUNK][S_];

    float (*h2_s)[128] = (float(*)[128])&aev_s[0][0];
    float (*h3_s)[96]  = (float(*)[96])(&aev_s[0][0] + MCHUNK * 128);

    if (t < A_) elem_s[t] = element_idxs[c * A_ + t];
    __syncthreads();
    if (t == 0) {
        int n = 0;
        for (int a = 0; a < A_; ++a) if (elem_s[a] == s) list_s[n++] = a;
        count_s = n;
    }
    __syncthreads();
    const int count = count_s;

    const float* W1s = W1 + s * (FAEV * 160);
    const float* b1s = b1 + s * 160;
    const float* W2s = W2 + s * (160 * 128);
    const float* b2s = b2 + s * 128;
    const float* W3s = W3 + s * (128 * 96);
    const float* b3s = b3 + s * 96;
    const float* W4s = W4 + s * 96;
    const float* b4s = b4 + s;

    // per-lane constants for the per-atom (half-wave) phases
    const int wave   = t >> 6;
    const int lane   = t & 63;
    const int half   = lane >> 5;
    const int slot   = wave * 2 + half;   // 0..7 : atom slot (== m, since MCHUNK==8)
    const int lane32 = lane & 31;
    const int zz = lane32 >> 2;           // angular z index 0..7
    const int yy = lane32 & 3;            // angular y index 0..3
    const float cz2 = 0.5f * __cosf(((float)zz + 0.5f) * (PI_F / 8.0f));
    const float sz2 = 0.5f * __sinf(((float)zz + 0.5f) * (PI_F / 8.0f));
    const float shfa_l = 0.9f + 0.65f * (float)yy;
    const float shfr_l = 0.9f + 0.26875f * (float)(lane32 & 15);
    const int   spg    = lane32 >> 4;     // 0 or 1 : radial species group

    for (int ch = ch0; ch * MCHUNK < count; ch += 2) {
        const int m0 = ch * MCHUNK;
        const int Mcur = min(MCHUNK, count - m0);

        // ---- phase 1: load + precompute neighbor data ----
        if (t < MCHUNK * K_) {
            int m = t / K_, k = t % K_;
            if (m < Mcur) {
                int a = list_s[m0 + m];
                int base = (c * A_ + a) * K_ + k;
                int nb = neighbor_idxs[base];
                float d = distances[base];
                float inv = __builtin_amdgcn_rcpf(d);
                float4 u;
                u.x = diff_vectors[base * 3 + 0] * inv;
                u.y = diff_vectors[base * 3 + 1] * inv;
                u.z = diff_vectors[base * 3 + 2] * inv;
                u.w = d;
                u4_s[m][k] = u;
                spec_s[m][k] = elem_s[nb];
                fcr_s[m][k] = (d < RCR) ? (0.5f * __cosf(PI_F * d * (1.0f / RCR)) + 0.5f) : 0.0f;
                fca_s[m][k] = (d < RCA) ? (0.5f * __cosf(PI_F * d * (1.0f / RCA)) + 0.5f) : 0.0f;
            } else {
                u4_s[m][k] = make_float4(0.f, 0.f, 0.f, 1.f);
                spec_s[m][k] = 0;
                fcr_s[m][k] = 0.f;
                fca_s[m][k] = 0.f;
            }
        }
        __syncthreads();

        // ---- phase 2: bucket active neighbors by species ----
        if (t < MCHUNK * S_) {
            int m = t >> 2, sp = t & 3;
            int n = 0;
            #pragma unroll
            for (int k = 0; k < K_; ++k)
                if (fca_s[m][k] > 0.0f && spec_s[m][k] == sp) bidx_s[m][sp][n++] = k;
            nsp_s[m][sp] = n;
        }
        __syncthreads();

        // ---- phase 3: per-atom AEV, half-wave per atom, lane = feature ----
        {
            const int m = slot;
            if (m < Mcur) {
                // radial: lane owns features lane32 (species spg) and 32+lane32 (species 2+spg)
                float acc0 = 0.0f, acc1 = 0.0f;
                #pragma unroll
                for (int k = 0; k < K_; ++k) {
                    float d   = u4_s[m][k].w;
                    float fcr = fcr_s[m][k];
                    int   sp  = spec_s[m][k];
                    float df  = d - shfr_l;
                    float term = 0.25f * __expf(-ETA_R * df * df) * fcr;
                    if (sp == spg)     acc0 += term;
                    if (sp == 2 + spg) acc1 += term;
                }
                aev_s[m][lane32]      = acc0;
                aev_s[m][32 + lane32] = acc1;

                // angular: 10 species-pair segments, compile-time pidx,
                // register accumulator, one plain LDS store per segment.
                auto pair_term = [&](const float4& u1, float fca1, int k) -> float {
                    float4 u2 = u4_s[m][k];
                    float fca2 = fca_s[m][k];
                    float ca = 0.95f * (u1.x * u2.x + u1.y * u2.y + u1.z * u2.z);
                    float sa = sqrtf(fmaxf(0.0f, 1.0f - ca * ca));
                    float hs = 0.5f * (u1.w + u2.w);
                    float dd = hs - shfa_l;
                    float f2 = __expf(-ETA_A * dd * dd);
                    float x  = 0.5f + ca * cz2 + sa * sz2;
                    float x2 = x * x, x4 = x2 * x2, x8 = x4 * x4, x16 = x8 * x8;
                    return (x16 * x16) * f2 * (2.0f * fca1 * fca2);
                };
                #pragma unroll
                for (int spa = 0; spa < 4; ++spa) {
                    #pragma unroll
                    for (int spb = spa; spb < 4; ++spb) {
                        const int pidx = spa * (9 - spa) / 2 + (spb - spa);
                        float acc = 0.0f;
                        const int na = nsp_s[m][spa];
                        const int nb = nsp_s[m][spb];
                        if (spa == spb) {
                            for (int jj = 0; jj < na - 1; ++jj) {
                                int j = bidx_s[m][spa][jj];
                                float4 u1 = u4_s[m][j];
                                float fca1 = fca_s[m][j];
                                for (int kk = jj + 1; kk < na; ++kk)
                                    acc += pair_term(u1, fca1, bidx_s[m][spa][kk]);
                            }
                        } else {
                            for (int jj = 0; jj < na; ++jj) {
                                int j = bidx_s[m][spa][jj];
                                float4 u1 = u4_s[m][j];
                                float fca1 = fca_s[m][j];
                                for (int kk = 0; kk < nb; ++kk)
                                    acc += pair_term(u1, fca1, bidx_s[m][spb][kk]);
                            }
                        }
                        aev_s[m][64 + pidx * 32 + lane32] = acc;
                    }
                }
            }
        }
        __syncthreads();

        // ---- layer 1: 384 -> 160 ----
        if (t < 160) {
            float acc[MCHUNK];
            #pragma unroll
            for (int m = 0; m < MCHUNK; ++m) acc[m] = 0.0f;
            for (int f = 0; f < FAEV; f += 4) {
                float w0 = W1s[(f + 0) * 160 + t];
                float w1 = W1s[(f + 1) * 160 + t];
                float w2 = W1s[(f + 2) * 160 + t];
                float w3 = W1s[(f + 3) * 160 + t];
                #pragma unroll
                for (int m = 0; m < MCHUNK; ++m) {
                    float4 av = *(const float4*)&aev_s[m][f];
                    acc[m] += av.x * w0 + av.y * w1 + av.z * w2 + av.w * w3;
                }
            }
            float bb = b1s[t];
            #pragma unroll
            for (int m = 0; m < MCHUNK; ++m) {
                float x = acc[m] + bb;
                h1_s[m][t] = (x > 0.0f) ? x : 0.1f * expm1f(10.0f * x);
            }
        }
        __syncthreads();   // after this, aev_s is dead -> reuse as h2/h3

        // ---- layer 2: 160 -> 128 (writes h2 overlay on aev) ----
        if (t < 128) {
            float acc[MCHUNK];
            #pragma unroll
            for (int m = 0; m < MCHUNK; ++m) acc[m] = 0.0f;
            for (int f = 0; f < 160; f += 4) {
                float w0 = W2s[(f + 0) * 128 + t];
                float w1 = W2s[(f + 1) * 128 + t];
                float w2 = W2s[(f + 2) * 128 + t];
                float w3 = W2s[(f + 3) * 128 + t];
                #pragma unroll
                for (int m = 0; m < MCHUNK; ++m) {
                    float4 av = *(const float4*)&h1_s[m][f];
                    acc[m] += av.x * w0 + av.y * w1 + av.z * w2 + av.w * w3;
                }
            }
            float bb = b2s[t];
            #pragma unroll
            for (int m = 0; m < MCHUNK; ++m) {
                float x = acc[m] + bb;
                h2_s[m][t] = (x > 0.0f) ? x : 0.1f * expm1f(10.0f * x);
            }
        }
        __syncthreads();

        // ---- layer 3: 128 -> 96 (writes h3 overlay) ----
        if (t < 96) {
            float acc[MCHUNK];
            #pragma unroll
            for (int m = 0; m < MCHUNK; ++m) acc[m] = 0.0f;
            for (int f = 0; f < 128; f += 4) {
                float w0 = W3s[(f + 0) * 96 + t];
                float w1 = W3s[(f + 1) * 96 + t];
                float w2 = W3s[(f + 2) * 96 + t];
                float w3 = W3s[(f + 3) * 96 + t];
                #pragma unroll
                for (int m = 0; m < MCHUNK; ++m) {
                    float4 av = *(const float4*)&h2_s[m][f];
                    acc[m] += av.x * w0 + av.y * w1 + av.z * w2 + av.w * w3;
                }
            }
            float bb = b3s[t];
            #pragma unroll
            for (int m = 0; m < MCHUNK; ++m) {
                float x = acc[m] + bb;
                h3_s[m][t] = (x > 0.0f) ? x : 0.1f * expm1f(10.0f * x);
            }
        }
        __syncthreads();

        // ---- layer 4: 96 -> 1, accumulate per molecule ----
        if (t < Mcur) {
            float e = b4s[0];
            for (int f = 0; f < 96; ++f) e += h3_s[t][f] * W4s[f];
            atomicAdd(&out[c], e);
        }
        __syncthreads();   // protect LDS before next chunk overwrites it
    }
}

extern "C" void kernel_launch(void* const* d_in, const int* in_sizes, int n_in,
                              void* d_out, int out_size, void* d_ws, size_t ws_size,
                              hipStream_t stream) {
    const int*   element_idxs  = (const int*)d_in[0];
    const int*   neighbor_idxs = (const int*)d_in[1];
    const float* distances     = (const float*)d_in[2];
    const float* diff_vectors  = (const float*)d_in[3];
    const float* W1 = (const float*)d_in[4];
    const float* b1 = (const float*)d_in[5];
    const float* W2 = (const float*)d_in[6];
    const float* b2 = (const float*)d_in[7];
    const float* W3 = (const float*)d_in[8];
    const float* b3 = (const float*)d_in[9];
    const float* W4 = (const float*)d_in[10];
    const float* b4 = (const float*)d_in[11];
    float* out = (float*)d_out;

    hipLaunchKernelGGL(zero_out_kernel, dim3(1), dim3(128), 0, stream, out);
    hipLaunchKernelGGL(aev_mlp_kernel, dim3(C_ * S_ * 2), dim3(256), 0, stream,
                       element_idxs, neighbor_idxs, distances, diff_vectors,
                       W1, b1, W2, b2, W3, b3, W4, b4, out);
}

// Round 4
// 305.182 us; speedup vs baseline: 1.7866x; 1.1017x over previous
//
#include <hip/hip_runtime.h>
#include <math.h>

// Problem constants
constexpr int C_ = 128, A_ = 64, K_ = 24, S_ = 4;
constexpr int NATOM = C_ * A_;    // 8192
constexpr int FAEV = 384;         // 64 radial + 320 angular
constexpr float RCR = 5.2f, RCA = 3.5f;
constexpr float ETA_R = 16.0f, ETA_A = 8.0f;
constexpr float PI_F = 3.14159265358979323846f;

// ---------------- kernel Z: zero out + species counters ----------------
__global__ void zero_kernel(float* out, int* cnt) {
    int t = threadIdx.x;
    if (t < C_) out[t] = 0.0f;
    if (t < S_) cnt[t] = 0;
}

// ---------------- kernel L: build per-species atom lists ----------------
__global__ __launch_bounds__(256) void list_kernel(const int* __restrict__ element_idxs,
                                                   int* __restrict__ cnt,
                                                   int* __restrict__ lists) {
    int atom = blockIdx.x * 256 + threadIdx.x;
    if (atom < NATOM) {
        int s = element_idxs[atom];
        int pos = atomicAdd(&cnt[s], 1);
        lists[s * NATOM + pos] = atom;
    }
}

// ---------------- kernel A: AEV for 8 atoms per block ----------------
__global__ __launch_bounds__(256) void aev_kernel(const int* __restrict__ element_idxs,
                                                  const int* __restrict__ neighbor_idxs,
                                                  const float* __restrict__ distances,
                                                  const float* __restrict__ diff_vectors,
                                                  float* __restrict__ aev_out) {
    const int blk = blockIdx.x;          // handles atoms blk*8 .. blk*8+7 (same molecule)
    const int c   = blk >> 3;            // molecule
    const int t   = threadIdx.x;

    __shared__ int    elem_s[A_];
    __shared__ float4 u4_s[8][K_];       // {ux,uy,uz,d}
    __shared__ float  fcr_s[8][K_];
    __shared__ float  fca_s[8][K_];
    __shared__ int    spec_s[8][K_];
    __shared__ int    bidx_s[8][S_][K_];
    __shared__ int    nsp_s[8][S_];

    if (t < A_) elem_s[t] = element_idxs[c * A_ + t];
    __syncthreads();

    // load + precompute neighbor data (192 threads: 8 atoms x 24 nbrs)
    if (t < 8 * K_) {
        int m = t / K_, k = t % K_;
        int base = (blk * 8 + m) * K_ + k;
        int nb = neighbor_idxs[base];
        float d = distances[base];
        float inv = __builtin_amdgcn_rcpf(d);
        float4 u;
        u.x = diff_vectors[base * 3 + 0] * inv;
        u.y = diff_vectors[base * 3 + 1] * inv;
        u.z = diff_vectors[base * 3 + 2] * inv;
        u.w = d;
        u4_s[m][k] = u;
        spec_s[m][k] = elem_s[nb];
        fcr_s[m][k] = (d < RCR) ? (0.5f * __cosf(PI_F * d * (1.0f / RCR)) + 0.5f) : 0.0f;
        fca_s[m][k] = (d < RCA) ? (0.5f * __cosf(PI_F * d * (1.0f / RCA)) + 0.5f) : 0.0f;
    }
    __syncthreads();

    // bucket active neighbors by species (32 threads)
    if (t < 8 * S_) {
        int m = t >> 2, sp = t & 3;
        int n = 0;
        #pragma unroll
        for (int k = 0; k < K_; ++k)
            if (fca_s[m][k] > 0.0f && spec_s[m][k] == sp) bidx_s[m][sp][n++] = k;
        nsp_s[m][sp] = n;
    }
    __syncthreads();

    // per-atom phase: half-wave per atom, lane = feature
    const int wave   = t >> 6;
    const int lane   = t & 63;
    const int half   = lane >> 5;
    const int m      = wave * 2 + half;   // 0..7
    const int lane32 = lane & 31;
    const int zz = lane32 >> 2;
    const int yy = lane32 & 3;
    const float cz2 = 0.5f * __cosf(((float)zz + 0.5f) * (PI_F / 8.0f));
    const float sz2 = 0.5f * __sinf(((float)zz + 0.5f) * (PI_F / 8.0f));
    const float shfa_l = 0.9f + 0.65f * (float)yy;
    const float shfr_l = 0.9f + 0.26875f * (float)(lane32 & 15);
    const int   spg    = lane32 >> 4;

    float* aev = aev_out + (blk * 8 + m) * FAEV;

    // radial: lane owns features lane32 (species spg) and 32+lane32 (species 2+spg)
    {
        float acc0 = 0.0f, acc1 = 0.0f;
        #pragma unroll
        for (int k = 0; k < K_; ++k) {
            float d   = u4_s[m][k].w;
            float fcr = fcr_s[m][k];
            int   sp  = spec_s[m][k];
            float df  = d - shfr_l;
            float term = 0.25f * __expf(-ETA_R * df * df) * fcr;
            if (sp == spg)     acc0 += term;
            if (sp == 2 + spg) acc1 += term;
        }
        aev[lane32]      = acc0;
        aev[32 + lane32] = acc1;
    }

    // angular: 10 species-pair segments, compile-time pidx, register accumulator
    {
        auto pair_term = [&](const float4& u1, float fca1, int k) -> float {
            float4 u2 = u4_s[m][k];
            float fca2 = fca_s[m][k];
            float ca = 0.95f * (u1.x * u2.x + u1.y * u2.y + u1.z * u2.z);
            float sa = sqrtf(fmaxf(0.0f, 1.0f - ca * ca));
            float hs = 0.5f * (u1.w + u2.w);
            float dd = hs - shfa_l;
            float f2 = __expf(-ETA_A * dd * dd);
            float x  = 0.5f + ca * cz2 + sa * sz2;
            float x2 = x * x, x4 = x2 * x2, x8 = x4 * x4, x16 = x8 * x8;
            return (x16 * x16) * f2 * (2.0f * fca1 * fca2);
        };
        #pragma unroll
        for (int spa = 0; spa < 4; ++spa) {
            #pragma unroll
            for (int spb = spa; spb < 4; ++spb) {
                const int pidx = spa * (9 - spa) / 2 + (spb - spa);
                float acc = 0.0f;
                const int na = nsp_s[m][spa];
                const int nb = nsp_s[m][spb];
                if (spa == spb) {
                    for (int jj = 0; jj < na - 1; ++jj) {
                        int j = bidx_s[m][spa][jj];
                        float4 u1 = u4_s[m][j];
                        float fca1 = fca_s[m][j];
                        for (int kk = jj + 1; kk < na; ++kk)
                            acc += pair_term(u1, fca1, bidx_s[m][spa][kk]);
                    }
                } else {
                    for (int jj = 0; jj < na; ++jj) {
                        int j = bidx_s[m][spa][jj];
                        float4 u1 = u4_s[m][j];
                        float fca1 = fca_s[m][j];
                        for (int kk = 0; kk < nb; ++kk)
                            acc += pair_term(u1, fca1, bidx_s[m][spb][kk]);
                    }
                }
                aev[64 + pidx * 32 + lane32] = acc;
            }
        }
    }
}

// ---------------- kernel B: MLP for 8 atoms of one species per block ----------------
__global__ __launch_bounds__(256) void mlp_kernel(const float* __restrict__ aev_ws,
                                                  const int* __restrict__ cnt,
                                                  const int* __restrict__ lists,
                                                  const float* __restrict__ W1, const float* __restrict__ b1,
                                                  const float* __restrict__ W2, const float* __restrict__ b2,
                                                  const float* __restrict__ W3, const float* __restrict__ b3,
                                                  const float* __restrict__ W4, const float* __restrict__ b4,
                                                  float* __restrict__ out) {
    const int s    = blockIdx.x & 3;
    const int tile = blockIdx.x >> 2;
    const int base = tile * 8;
    const int cntS = cnt[s];
    if (base >= cntS) return;
    const int matoms = min(8, cntS - base);
    const int t = threadIdx.x;

    __shared__ float aev_s[8][FAEV];     // overlays h2 (8x128) + h3 (8x96) later
    __shared__ float h1_s[8][160];
    __shared__ int   atom_s[8];
    float (*h2_s)[128] = (float(*)[128])&aev_s[0][0];
    float (*h3_s)[96]  = (float(*)[96])(&aev_s[0][0] + 8 * 128);

    // load tile: row m handled by 32 lanes, 3 float4 each
    {
        int m = t >> 5, l = t & 31;
        int atom = (m < matoms) ? lists[s * NATOM + base + m] : -1;
        if (l == 0) atom_s[m] = atom;
        const float4* src = (const float4*)(aev_ws + (long)max(atom, 0) * FAEV);
        float4* dst = (float4*)&aev_s[m][0];
        #pragma unroll
        for (int i = 0; i < 3; ++i) {
            float4 v = (atom >= 0) ? src[l + 32 * i] : make_float4(0.f, 0.f, 0.f, 0.f);
            dst[l + 32 * i] = v;
        }
    }
    __syncthreads();

    const float* W1s = W1 + s * (FAEV * 160);
    const float* b1s = b1 + s * 160;
    const float* W2s = W2 + s * (160 * 128);
    const float* b2s = b2 + s * 128;
    const float* W3s = W3 + s * (128 * 96);
    const float* b3s = b3 + s * 96;
    const float* W4s = W4 + s * 96;
    const float* b4s = b4 + s;

    // ---- layer 1: 384 -> 160 ----
    if (t < 160) {
        float acc[8];
        #pragma unroll
        for (int m = 0; m < 8; ++m) acc[m] = 0.0f;
        for (int f = 0; f < FAEV; f += 4) {
            float w0 = W1s[(f + 0) * 160 + t];
            float w1 = W1s[(f + 1) * 160 + t];
            float w2 = W1s[(f + 2) * 160 + t];
            float w3 = W1s[(f + 3) * 160 + t];
            #pragma unroll
            for (int m = 0; m < 8; ++m) {
                float4 av = *(const float4*)&aev_s[m][f];
                acc[m] += av.x * w0 + av.y * w1 + av.z * w2 + av.w * w3;
            }
        }
        float bb = b1s[t];
        #pragma unroll
        for (int m = 0; m < 8; ++m) {
            float x = acc[m] + bb;
            h1_s[m][t] = (x > 0.0f) ? x : 0.1f * expm1f(10.0f * x);
        }
    }
    __syncthreads();   // aev_s dead -> reuse as h2/h3

    // ---- layer 2: 160 -> 128 ----
    if (t < 128) {
        float acc[8];
        #pragma unroll
        for (int m = 0; m < 8; ++m) acc[m] = 0.0f;
        for (int f = 0; f < 160; f += 4) {
            float w0 = W2s[(f + 0) * 128 + t];
            float w1 = W2s[(f + 1) * 128 + t];
            float w2 = W2s[(f + 2) * 128 + t];
            float w3 = W2s[(f + 3) * 128 + t];
            #pragma unroll
            for (int m = 0; m < 8; ++m) {
                float4 av = *(const float4*)&h1_s[m][f];
                acc[m] += av.x * w0 + av.y * w1 + av.z * w2 + av.w * w3;
            }
        }
        float bb = b2s[t];
        #pragma unroll
        for (int m = 0; m < 8; ++m) {
            float x = acc[m] + bb;
            h2_s[m][t] = (x > 0.0f) ? x : 0.1f * expm1f(10.0f * x);
        }
    }
    __syncthreads();

    // ---- layer 3: 128 -> 96 ----
    if (t < 96) {
        float acc[8];
        #pragma unroll
        for (int m = 0; m < 8; ++m) acc[m] = 0.0f;
        for (int f = 0; f < 128; f += 4) {
            float w0 = W3s[(f + 0) * 96 + t];
            float w1 = W3s[(f + 1) * 96 + t];
            float w2 = W3s[(f + 2) * 96 + t];
            float w3 = W3s[(f + 3) * 96 + t];
            #pragma unroll
            for (int m = 0; m < 8; ++m) {
                float4 av = *(const float4*)&h2_s[m][f];
                acc[m] += av.x * w0 + av.y * w1 + av.z * w2 + av.w * w3;
            }
        }
        float bb = b3s[t];
        #pragma unroll
        for (int m = 0; m < 8; ++m) {
            float x = acc[m] + bb;
            h3_s[m][t] = (x > 0.0f) ? x : 0.1f * expm1f(10.0f * x);
        }
    }
    __syncthreads();

    // ---- layer 4: 96 -> 1, accumulate per molecule ----
    if (t < matoms) {
        float e = b4s[0];
        for (int f = 0; f < 96; ++f) e += h3_s[t][f] * W4s[f];
        atomicAdd(&out[atom_s[t] >> 6], e);
    }
}

extern "C" void kernel_launch(void* const* d_in, const int* in_sizes, int n_in,
                              void* d_out, int out_size, void* d_ws, size_t ws_size,
                              hipStream_t stream) {
    const int*   element_idxs  = (const int*)d_in[0];
    const int*   neighbor_idxs = (const int*)d_in[1];
    const float* distances     = (const float*)d_in[2];
    const float* diff_vectors  = (const float*)d_in[3];
    const float* W1 = (const float*)d_in[4];
    const float* b1 = (const float*)d_in[5];
    const float* W2 = (const float*)d_in[6];
    const float* b2 = (const float*)d_in[7];
    const float* W3 = (const float*)d_in[8];
    const float* b3 = (const float*)d_in[9];
    const float* W4 = (const float*)d_in[10];
    const float* b4 = (const float*)d_in[11];
    float* out = (float*)d_out;

    // workspace layout
    float* aev_ws = (float*)d_ws;                                  // 8192*384 f32 = 12.58 MB
    int*   cnt    = (int*)((char*)d_ws + (size_t)NATOM * FAEV * 4); // 4 ints
    int*   lists  = cnt + 4;                                        // 4*8192 ints

    hipLaunchKernelGGL(zero_kernel, dim3(1), dim3(256), 0, stream, out, cnt);
    hipLaunchKernelGGL(list_kernel, dim3(NATOM / 256), dim3(256), 0, stream,
                       element_idxs, cnt, lists);
    hipLaunchKernelGGL(aev_kernel, dim3(NATOM / 8), dim3(256), 0, stream,
                       element_idxs, neighbor_idxs, distances, diff_vectors, aev_ws);
    hipLaunchKernelGGL(mlp_kernel, dim3(4 * 384), dim3(256), 0, stream,
                       aev_ws, cnt, lists, W1, b1, W2, b2, W3, b3, W4, b4, out);
}